// Round 9
// baseline (367.322 us; speedup 1.0000x reference)
//
#include <hip/hip_runtime.h>
#include <hip/hip_bf16.h>

// Problem constants (match reference)
#define NN 100000
#define EE 1000000
#define FDIM 64
#define NREL 16
#define NBASE 8
#define HN (NN * FDIM)
#define H4 (HN / 4)
#define NB_SCAN ((NN + 255) / 256) // 391 scan blocks
#define NBLK (NN / 8)              // 12500 blocks (8 nodes each)

typedef __attribute__((ext_vector_type(8))) short short8;
typedef __attribute__((ext_vector_type(4))) float f32x4;

static __device__ __forceinline__ ushort f2bf(float f) {
    __hip_bfloat16 b = __float2bfloat16(f);
    return *(ushort*)&b;
}
static __device__ __forceinline__ float bf2f(ushort u) {
    unsigned x = ((unsigned)u) << 16;
    float f;
    __builtin_memcpy(&f, &x, 4);
    return f;
}

// ---------------------------------------------------------------------------
// Algebra (harness-verified):
//   h2[n][o] = sum_k T[n][k] * weight_flat[k*64+o],  k = 32*rel + (q*8+b)
//   T[n][32*rel + j] += G[src][j];  G[s][q*8+b] = sum_m h[s][16q+m]*w_comp[m][b]
// Gather register mapping: lane L holds T[n][k], k = L + 64*m (m=0..7).
// Edge (src,r): lanes with (L>>5)==(r&1), reg m=r>>1, col j=L&31.
//
// L2 strategy: G (6.4 MB) must stay L2-resident across the random gather.
// All stream-once traffic (pidx, h2, src/dst/rel, h, out) is non-temporal
// so it does not evict G. FETCH_SIZE showed 91% of G-row reads missing L2
// before this change.
// ---------------------------------------------------------------------------

__global__ __launch_bounds__(256) void zero_cnt_kernel(int* __restrict__ cnt) {
    int i = blockIdx.x * 256 + threadIdx.x;
    if (i < NN) cnt[i] = 0;
}

// prep2: fused dst-histogram (fire-and-forget atomics overlap streaming);
// bf16 weight transpose WbT[o][k=512]; G bf16 [N][32]; relu out.
__global__ __launch_bounds__(256) void prep2_kernel(
    const f32x4* __restrict__ h4, f32x4* __restrict__ out4,
    const float* __restrict__ h, const float* __restrict__ weight,
    const float* __restrict__ w_comp, ushort* __restrict__ G,
    ushort* __restrict__ WbTh, const int* __restrict__ dst,
    int* __restrict__ cnt) {
    __shared__ float wc[128];
    if (threadIdx.x < 128) wc[threadIdx.x] = w_comp[threadIdx.x];
    int gid = blockIdx.x * 256 + threadIdx.x;
    // fused dst histogram (cnt pre-zeroed by zero_cnt_kernel)
    {
        int stride = gridDim.x * 256;
        for (int i = gid; i < EE; i += stride) {
            int d = __builtin_nontemporal_load(dst + i);
            atomicAdd(&cnt[d], 1);          // no-return atomic: non-blocking
        }
    }
    __syncthreads();
    if (gid < 32768) {                       // WbT[o][k] = weight_flat[k*64+o]
        int o = gid >> 9, k = gid & 511;
        WbTh[gid] = f2bf(weight[k * 64 + o]);
    }
    if (gid < NN * 4) {                      // G[n][q*8+b] (bf16) -- keep cached
        int n = gid >> 2, q = gid & 3;
        const f32x4* hp = h4 + (size_t)n * 16 + q * 4;
        float hv[16];
#pragma unroll
        for (int m4 = 0; m4 < 4; ++m4) {
            f32x4 v = __builtin_nontemporal_load(hp + m4);
            hv[4 * m4 + 0] = v[0]; hv[4 * m4 + 1] = v[1];
            hv[4 * m4 + 2] = v[2]; hv[4 * m4 + 3] = v[3];
        }
        float accb[8];
#pragma unroll
        for (int b = 0; b < 8; ++b) accb[b] = 0.f;
#pragma unroll
        for (int m = 0; m < 16; ++m) {
            float hm = hv[m];
#pragma unroll
            for (int b = 0; b < 8; ++b)
                accb[b] = fmaf(hm, wc[m * 8 + b], accb[b]);
        }
        short8 gv;
#pragma unroll
        for (int b = 0; b < 8; ++b) gv[b] = (short)f2bf(accb[b]);
        ((short8*)G)[gid] = gv;
    }
    if (gid < H4) {                          // relu output (stream-once)
        f32x4 v = __builtin_nontemporal_load(h4 + gid);
        v[0] = fmaxf(v[0], 0.f); v[1] = fmaxf(v[1], 0.f);
        v[2] = fmaxf(v[2], 0.f); v[3] = fmaxf(v[3], 0.f);
        __builtin_nontemporal_store(v, out4 + gid);
    }
}

// ---- multi-block exclusive scan of the 100k dst-histogram (3 tiny stages) ----
__global__ __launch_bounds__(256) void scan_a_kernel(const int* __restrict__ cnt,
                                                     int* __restrict__ bsum) {
    int i = blockIdx.x * 256 + threadIdx.x;
    int v = (i < NN) ? cnt[i] : 0;
#pragma unroll
    for (int o = 32; o > 0; o >>= 1) v += __shfl_down(v, o, 64);
    __shared__ int ws4[4];
    if ((threadIdx.x & 63) == 0) ws4[threadIdx.x >> 6] = v;
    __syncthreads();
    if (threadIdx.x == 0) bsum[blockIdx.x] = ws4[0] + ws4[1] + ws4[2] + ws4[3];
}

__global__ __launch_bounds__(512) void scan_b_kernel(const int* __restrict__ bsum,
                                                     int* __restrict__ bbase,
                                                     int* __restrict__ off) {
    __shared__ int lds[512];
    int t = threadIdx.x;
    int v = (t < NB_SCAN) ? bsum[t] : 0;
    lds[t] = v;
    __syncthreads();
    for (int o = 1; o < 512; o <<= 1) {
        int u = (t >= o) ? lds[t - o] : 0;
        __syncthreads();
        lds[t] += u;
        __syncthreads();
    }
    if (t < NB_SCAN) bbase[t] = lds[t] - v;
    if (t == NB_SCAN - 1) off[NN] = lds[t];
}

__global__ __launch_bounds__(256) void scan_c_kernel(const int* __restrict__ cnt,
                                                     const int* __restrict__ bbase,
                                                     int* __restrict__ off,
                                                     int* __restrict__ cur) {
    __shared__ int lds[256];
    int i = blockIdx.x * 256 + threadIdx.x;
    int t = threadIdx.x;
    int v = (i < NN) ? cnt[i] : 0;
    lds[t] = v;
    __syncthreads();
    for (int o = 1; o < 256; o <<= 1) {
        int u = (t >= o) ? lds[t - o] : 0;
        __syncthreads();
        lds[t] += u;
        __syncthreads();
    }
    if (i < NN) {
        int excl = lds[t] - v + bbase[blockIdx.x];
        off[i] = excl;
        cur[i] = excl;
    }
}

// Bucket edges by dst; payload p = src*16 + rel. Stream-once traffic is
// non-temporal so it doesn't evict G/WbTh from L2.
__global__ void scatter_dst_kernel(const int* __restrict__ src, const int* __restrict__ dst,
                                   const int* __restrict__ rel, int* __restrict__ cur,
                                   int* __restrict__ pidx) {
    int i = blockIdx.x * blockDim.x + threadIdx.x;
    if (i < EE) {
        int d = __builtin_nontemporal_load(dst + i);
        int s = __builtin_nontemporal_load(src + i);
        int r = __builtin_nontemporal_load(rel + i);
        int pos = atomicAdd(&cur[d], 1);
        __builtin_nontemporal_store((s << 4) | r, pidx + pos);
    }
}

// Per-edge accumulate into lane registers (selected by r>>1 / half parity).
#define ACC8(p, gu)                                                          \
    {                                                                        \
        int r_ = (p) & 15;                                                   \
        float gv_ = ((r_ & 1) == half) ? bf2f(gu) : 0.f;                     \
        int m_ = r_ >> 1;                                                    \
        a0 += (m_ == 0) ? gv_ : 0.f;                                         \
        a1 += (m_ == 1) ? gv_ : 0.f;                                         \
        a2 += (m_ == 2) ? gv_ : 0.f;                                         \
        a3 += (m_ == 3) ? gv_ : 0.f;                                         \
        a4 += (m_ == 4) ? gv_ : 0.f;                                         \
        a5 += (m_ == 5) ? gv_ : 0.f;                                         \
        a6 += (m_ == 6) ? gv_ : 0.f;                                         \
        a7 += (m_ == 7) ? gv_ : 0.f;                                         \
    }

// Fused aggregate + projection: 8 waves/block, one wave per dst node,
// T in 8 registers/lane, 4-deep load batches; regs -> LDS; MFMA epilogue.
// pidx loads + h2 stores non-temporal (G-residency protection).
__global__ __launch_bounds__(512, 8) void agg_proj_kernel(
    const int* __restrict__ off, const int* __restrict__ pidx,
    const ushort* __restrict__ G, const ushort* __restrict__ WbTh,
    float* __restrict__ h2) {
    __shared__ __align__(16) float T[8][516];
    const int t = threadIdx.x;
    const int wv = t >> 6;
    const int lane = t & 63;
    const int node0 = blockIdx.x * 8;

    {   // ---- gather: this wave owns node node0+wv ----
        const int node = node0 + wv;
        const int s = off[node], e = off[node + 1];
        const int col = lane & 31;           // j within the 32-value G row
        const int half = lane >> 5;          // parity selector
        float a0 = 0.f, a1 = 0.f, a2 = 0.f, a3 = 0.f;
        float a4 = 0.f, a5 = 0.f, a6 = 0.f, a7 = 0.f;
        int i = s;
        for (; i + 4 <= e; i += 4) {         // 4 independent row loads in flight
            int p0 = __builtin_nontemporal_load(pidx + i);
            int p1 = __builtin_nontemporal_load(pidx + i + 1);
            int p2 = __builtin_nontemporal_load(pidx + i + 2);
            int p3 = __builtin_nontemporal_load(pidx + i + 3);
            ushort g0 = G[(unsigned)(((p0 & ~15) << 1) + col)];
            ushort g1 = G[(unsigned)(((p1 & ~15) << 1) + col)];
            ushort g2 = G[(unsigned)(((p2 & ~15) << 1) + col)];
            ushort g3 = G[(unsigned)(((p3 & ~15) << 1) + col)];
            ACC8(p0, g0); ACC8(p1, g1); ACC8(p2, g2); ACC8(p3, g3);
        }
        for (; i < e; ++i) {
            int p0 = __builtin_nontemporal_load(pidx + i);
            ushort g0 = G[(unsigned)(((p0 & ~15) << 1) + col)];
            ACC8(p0, g0);
        }
        // regs -> LDS row wv: lane L holds k = L + 64m (conflict-free stores)
        T[wv][lane +   0] = a0; T[wv][lane +  64] = a1;
        T[wv][lane + 128] = a2; T[wv][lane + 192] = a3;
        T[wv][lane + 256] = a4; T[wv][lane + 320] = a5;
        T[wv][lane + 384] = a6; T[wv][lane + 448] = a7;
    }
    __syncthreads();

    if (wv < 4) {   // ---- MFMA epilogue: [8x512] @ [512x64], proven layout ----
        const int quad = lane >> 4, l15 = lane & 15;
        f32x4 acc = (f32x4){0.f, 0.f, 0.f, 0.f};
        const short8* bh = (const short8*)(WbTh + (size_t)(wv * 16 + l15) * 512);
#pragma unroll
        for (int kk = 0; kk < 16; ++kk) {
            const float* ap = &T[l15 & 7][kk * 32 + quad * 8];
            f32x4 q0 = *(const f32x4*)ap;
            f32x4 q1 = *(const f32x4*)(ap + 4);
            short8 ah;
#pragma unroll
            for (int i = 0; i < 4; ++i) {
                ah[i] = (short)f2bf(q0[i]);
                ah[4 + i] = (short)f2bf(q1[i]);
            }
            acc = __builtin_amdgcn_mfma_f32_16x16x32_bf16(ah, bh[kk * 4 + quad], acc, 0, 0, 0);
        }
        // C/D: col = lane&15, row = quad*4 + reg; rows 0..7 valid (quad<2).
        if (quad < 2) {
            float* hp = h2 + (size_t)(node0 + quad * 4) * 64 + wv * 16 + l15;
#pragma unroll
            for (int r = 0; r < 4; ++r)
                __builtin_nontemporal_store(acc[r], hp + (size_t)r * 64);
        }
    }
}

extern "C" void kernel_launch(void* const* d_in, const int* in_sizes, int n_in,
                              void* d_out, int out_size, void* d_ws, size_t ws_size,
                              hipStream_t stream) {
    const float* h      = (const float*)d_in[0];
    const float* weight = (const float*)d_in[1];
    const float* w_comp = (const float*)d_in[2];
    const int*   src    = (const int*)d_in[3];
    const int*   dst    = (const int*)d_in[4];
    const int*   rel    = (const int*)d_in[5];

    float* out_hnew = (float*)d_out;
    float* out_h2   = out_hnew + HN;

    char* ws = (char*)d_ws;

    // Workspace layout (16B-aligned); total ~12 MB
    ushort* WbTh  = (ushort*)ws;                    // 64 KB
    int*    cnt   = (int*)(ws + 131072);            // 100000 ints
    int*    off   = (int*)(ws + 531072);            // 100001 ints (+pad)
    int*    cur   = (int*)(ws + 931088);            // 100000 ints
    int*    pidx  = (int*)(ws + 1331088);           // 1M ints
    int*    bsum  = (int*)(ws + 5331088);           // 392 ints
    int*    bbase = (int*)(ws + 5332656);           // 392 ints
    ushort* G     = (ushort*)(ws + 5334224);        // N x 32 bf16 = 6.4 MB

    hipLaunchKernelGGL(zero_cnt_kernel, dim3(NB_SCAN), dim3(256), 0, stream, cnt);
    hipLaunchKernelGGL(prep2_kernel, dim3(H4 / 256), dim3(256), 0, stream,
                       (const f32x4*)h, (f32x4*)out_hnew, h, weight, w_comp,
                       G, WbTh, dst, cnt);
    hipLaunchKernelGGL(scan_a_kernel, dim3(NB_SCAN), dim3(256), 0, stream, cnt, bsum);
    hipLaunchKernelGGL(scan_b_kernel, dim3(1), dim3(512), 0, stream, bsum, bbase, off);
    hipLaunchKernelGGL(scan_c_kernel, dim3(NB_SCAN), dim3(256), 0, stream,
                       cnt, bbase, off, cur);
    hipLaunchKernelGGL(scatter_dst_kernel, dim3((EE + 255) / 256), dim3(256), 0, stream,
                       src, dst, rel, cur, pidx);
    hipLaunchKernelGGL(agg_proj_kernel, dim3(NBLK), dim3(512), 0, stream,
                       off, pidx, G, WbTh, out_h2);
}